// Round 4
// baseline (363.209 us; speedup 1.0000x reference)
//
#include <hip/hip_runtime.h>
#include <hip/hip_fp16.h>
#include <cstdint>

// MultiHeadSelfAttention: N=2, S=4096, D=1024, H=16, hd=64, fp32 in/out.
// fp32->f16 convert (Wq pre-scaled by 0.125*log2e) -> fused QKV GEMM (V
// transposed) -> flash attention (32x32 MFMA, swapped operands, exp2-domain
// in-register softmax, permlane packing, static-buffer unroll-2 pipeline).
// NOTE: cross-half reduce uses __shfl_xor, NOT permlane32_swap(x,x) — the
// aliased-operand in-place swap drops the lane's own half (round-3 bug).

typedef _Float16 f16;
typedef _Float16 f16x4_t __attribute__((ext_vector_type(4)));
typedef _Float16 f16x8_t __attribute__((ext_vector_type(8)));
typedef float f32x4_t __attribute__((ext_vector_type(4)));
typedef float f32x16_t __attribute__((ext_vector_type(16)));
typedef int i32x2_t __attribute__((ext_vector_type(2)));
typedef int i32x4_t __attribute__((ext_vector_type(4)));
typedef uint32_t u32;

#define NB 2
#define SEQ 4096
#define DM 1024
#define NH 16
#define HDIM 64

#define MFMA32 __builtin_amdgcn_mfma_f32_32x32x16_f16

__device__ __forceinline__ u32 swz128(u32 b) {
  return b ^ (((b >> 7) & 7u) << 4);
}
__device__ __forceinline__ u32 swz256(u32 b) {
  return b ^ (((b >> 8) & 15u) << 4);
}

__device__ __forceinline__ void gload_lds16(const void* g, void* l) {
  __builtin_amdgcn_global_load_lds(
      (const __attribute__((address_space(1))) uint32_t*)g,
      (__attribute__((address_space(3))) uint32_t*)l, 16, 0, 0);
}

// Cross-half (lane ^ 32) reduce. Must NOT use permlane32_swap(x,x): aliased
// operands make the in-place half-swap return partner twice, dropping own.
__device__ __forceinline__ float xhalf_max(float x) {
  return fmaxf(x, __shfl_xor(x, 32, 64));
}
__device__ __forceinline__ float xhalf_add(float x) {
  return x + __shfl_xor(x, 32, 64);
}

__global__ void cvt_f32_to_f16(const float* __restrict__ in,
                               f16* __restrict__ out, int n4) {
  int idx = blockIdx.x * blockDim.x + threadIdx.x;
  int stride = blockDim.x * gridDim.x;
  for (int i = idx; i < n4; i += stride) {
    float4 v = reinterpret_cast<const float4*>(in)[i];
    f16x4_t h;
    h[0] = (f16)v.x; h[1] = (f16)v.y; h[2] = (f16)v.z; h[3] = (f16)v.w;
    reinterpret_cast<f16x4_t*>(out)[i] = h;
  }
}

// Weight convert; Wq scaled by 0.125*log2(e) so softmax runs in exp2 domain.
__global__ void cvt_w3(const float* __restrict__ a, const float* __restrict__ b,
                       const float* __restrict__ c, f16* __restrict__ outw) {
  const int i = blockIdx.x * blockDim.x + threadIdx.x;
  const int n4 = DM * DM / 4;
  const float QS = 0.18033688f;  // 0.125 * log2(e)
  const float4 va = reinterpret_cast<const float4*>(a)[i];
  const float4 vb = reinterpret_cast<const float4*>(b)[i];
  const float4 vc = reinterpret_cast<const float4*>(c)[i];
  f16x4_t ha, hb, hc;
  ha[0]=(f16)(va.x*QS); ha[1]=(f16)(va.y*QS); ha[2]=(f16)(va.z*QS); ha[3]=(f16)(va.w*QS);
  hb[0]=(f16)vb.x; hb[1]=(f16)vb.y; hb[2]=(f16)vb.z; hb[3]=(f16)vb.w;
  hc[0]=(f16)vc.x; hc[1]=(f16)vc.y; hc[2]=(f16)vc.z; hc[3]=(f16)vc.w;
  reinterpret_cast<f16x4_t*>(outw)[i] = ha;
  reinterpret_cast<f16x4_t*>(outw)[n4 + i] = hb;
  reinterpret_cast<f16x4_t*>(outw)[2 * n4 + i] = hc;
}

// ---------------- fused QKV projection (proven round 1/2) ----------------
#define PBM 128
#define PBN 128
#define PBK 64

__launch_bounds__(256)
__global__ void qkv_proj(const f16* __restrict__ xb, const f16* __restrict__ wb,
                         f16* __restrict__ Qg, f16* __restrict__ Kg,
                         f16* __restrict__ Vt) {
  __shared__ f16 As[PBM * PBK];
  __shared__ f16 Bs[PBN * PBK];
  const int tid = threadIdx.x;
  const int wid = tid >> 6;
  const int lane = tid & 63;
  const int g = lane >> 4;
  const int r = lane & 15;
  const int mBase = blockIdx.x * PBM;
  const int nBase = blockIdx.y * PBN;
  const int wrow = wid >> 1, wcol = wid & 1;

  f32x4_t acc[4][4];
#pragma unroll
  for (int i = 0; i < 4; ++i)
#pragma unroll
    for (int j = 0; j < 4; ++j) acc[i][j] = (f32x4_t){0.f, 0.f, 0.f, 0.f};

  for (int kt = 0; kt < DM / PBK; ++kt) {
#pragma unroll
    for (int c4 = 0; c4 < 4; ++c4) {
      const int chunk = wid * 4 + c4;
      const u32 phys = chunk * 1024 + lane * 16;
      const u32 logb = swz128(phys);
      const u32 row = logb >> 7;
      const u32 colb = logb & 127;
      gload_lds16((const char*)xb + ((size_t)(mBase + row) * DM + kt * PBK) * 2 + colb,
                  (char*)As + (size_t)chunk * 1024);
      gload_lds16((const char*)wb + ((size_t)(nBase + row) * DM + kt * PBK) * 2 + colb,
                  (char*)Bs + (size_t)chunk * 1024);
    }
    __syncthreads();

#pragma unroll
    for (int kk = 0; kk < 2; ++kk) {
      f16x8_t a[4], b[4];
#pragma unroll
      for (int mi = 0; mi < 4; ++mi) {
        const u32 lb = ((u32)(wrow * 64 + mi * 16 + r) << 7) + kk * 64 + g * 16;
        a[mi] = *reinterpret_cast<const f16x8_t*>((const char*)As + swz128(lb));
      }
#pragma unroll
      for (int ni = 0; ni < 4; ++ni) {
        const u32 lb = ((u32)(wcol * 64 + ni * 16 + r) << 7) + kk * 64 + g * 16;
        b[ni] = *reinterpret_cast<const f16x8_t*>((const char*)Bs + swz128(lb));
      }
#pragma unroll
      for (int mi = 0; mi < 4; ++mi)
#pragma unroll
        for (int ni = 0; ni < 4; ++ni)
          acc[mi][ni] = __builtin_amdgcn_mfma_f32_16x16x32_f16(a[mi], b[ni],
                                                               acc[mi][ni], 0, 0, 0);
    }
    __syncthreads();
  }

  const int part = nBase >> 10;
#pragma unroll
  for (int mi = 0; mi < 4; ++mi) {
#pragma unroll
    for (int ni = 0; ni < 4; ++ni) {
      const int c = nBase + wcol * 64 + ni * 16 + r;
      const int hh = (c & 1023) >> 6;
      const int d = c & 63;
      const int m0 = mBase + wrow * 64 + mi * 16 + g * 4;
      const int n = m0 >> 12;
      const int s0 = m0 & 4095;
      if (part == 2) {
        f16x4_t v4;
#pragma unroll
        for (int q = 0; q < 4; ++q) v4[q] = (f16)acc[mi][ni][q];
        *reinterpret_cast<f16x4_t*>(
            Vt + ((size_t)((n * NH + hh) << 6) + d) * SEQ + s0) = v4;
      } else {
        f16* dst = (part == 0) ? Qg : Kg;
#pragma unroll
        for (int q = 0; q < 4; ++q)
          dst[((size_t)((n * NH + hh) * SEQ + s0 + q) << 6) + d] =
              (f16)acc[mi][ni][q];
      }
    }
  }
}

// ---------------- flash attention ----------------
// LDS map (bytes): K buf0 [0,8K) | K buf1 [8K,16K) | V buf0 [16K,24K) | V buf1 [24K,32K)
// Read offsets offj[j] (j = sub*4 + step) precomputed with swz256 baked in;
// buffer select and K/V select are compile-time immediates on the ds_read.

#define STAGE(BUFOFF, VOFF)                                              \
  do {                                                                   \
    gload_lds16(kp0, Sall + c0 * 1024 + (BUFOFF));                       \
    gload_lds16(kp1, Sall + c1 * 1024 + (BUFOFF));                       \
    gload_lds16(vp0 + (VOFF), Sall + 16384 + c0 * 1024 + (BUFOFF));      \
    gload_lds16(vp1 + (VOFF), Sall + 16384 + c1 * 1024 + (BUFOFF));      \
  } while (0)

#define COMPUTE(BUFOFF)                                                        \
  do {                                                                         \
    f32x16_t sacc[2][2];                                                       \
    _Pragma("unroll") for (int ksub = 0; ksub < 2; ++ksub) {                   \
      _Pragma("unroll") for (int cs = 0; cs < 4; ++cs) {                       \
        const f16x8_t kf = *reinterpret_cast<const f16x8_t*>(                  \
            Sall + offj[ksub * 4 + cs] + (BUFOFF));                            \
        if (cs == 0) {                                                         \
          sacc[0][ksub] = MFMA32(kf, qf[0][0], fz, 0, 0, 0);                   \
          sacc[1][ksub] = MFMA32(kf, qf[1][0], fz, 0, 0, 0);                   \
        } else {                                                               \
          sacc[0][ksub] = MFMA32(kf, qf[0][cs], sacc[0][ksub], 0, 0, 0);       \
          sacc[1][ksub] = MFMA32(kf, qf[1][cs], sacc[1][ksub], 0, 0, 0);       \
        }                                                                      \
      }                                                                        \
    }                                                                          \
    _Pragma("unroll") for (int qs = 0; qs < 2; ++qs) {                         \
      const f32x16_t sA = sacc[qs][0], sB = sacc[qs][1];                       \
      float u0 = fmaxf(fmaxf(sA[0], sA[1]), sA[2]);                            \
      float u1 = fmaxf(fmaxf(sA[3], sA[4]), sA[5]);                            \
      float u2 = fmaxf(fmaxf(sA[6], sA[7]), sA[8]);                            \
      float u3 = fmaxf(fmaxf(sA[9], sA[10]), sA[11]);                          \
      float u4 = fmaxf(fmaxf(sA[12], sA[13]), sA[14]);                         \
      float u5 = fmaxf(fmaxf(sB[0], sB[1]), sB[2]);                            \
      float u6 = fmaxf(fmaxf(sB[3], sB[4]), sB[5]);                            \
      float u7 = fmaxf(fmaxf(sB[6], sB[7]), sB[8]);                            \
      float u8 = fmaxf(fmaxf(sB[9], sB[10]), sB[11]);                          \
      float u9 = fmaxf(fmaxf(sB[12], sB[13]), sB[14]);                         \
      float u10 = fmaxf(sA[15], sB[15]);                                       \
      float v0 = fmaxf(fmaxf(u0, u1), u2);                                     \
      float v1 = fmaxf(fmaxf(u3, u4), u5);                                     \
      float v2 = fmaxf(fmaxf(u6, u7), u8);                                     \
      float v3 = fmaxf(u9, u10);                                               \
      float pm = fmaxf(fmaxf(fmaxf(v0, v1), v2), v3);                          \
      pm = xhalf_max(pm);                                                      \
      if (!__all(pm - m_[qs] <= 11.0f)) {                                      \
        const float mn = fmaxf(m_[qs], pm);                                    \
        const float sc = exp2f(m_[qs] - mn);                                   \
        o_[0][qs] *= sc;                                                       \
        o_[1][qs] *= sc;                                                       \
        l_[qs] *= sc;                                                          \
        m_[qs] = mn;                                                           \
      }                                                                        \
      const float mq = m_[qs];                                                 \
      float rs0 = 0.f, rs1 = 0.f, rs2 = 0.f, rs3 = 0.f;                        \
      _Pragma("unroll") for (int ks = 0; ks < 4; ++ks) {                       \
        const f32x16_t S = (ks < 2) ? sA : sB;                                 \
        const int b4 = 4 * (ks & 1);                                           \
        i32x4_t pw;                                                            \
        _Pragma("unroll") for (int t0 = 0; t0 < 2; ++t0) {                     \
          const int e = 2 * (b4 + t0);                                         \
          const float eA0 = exp2f(S[e] - mq);                                  \
          const float eA1 = exp2f(S[e + 1] - mq);                              \
          const float eB0 = exp2f(S[e + 4] - mq);                              \
          const float eB1 = exp2f(S[e + 5] - mq);                              \
          rs0 += eA0; rs1 += eA1; rs2 += eB0; rs3 += eB1;                      \
          const int A = __builtin_bit_cast(                                    \
              int, __builtin_amdgcn_cvt_pkrtz(eA0, eA1));                      \
          const int B = __builtin_bit_cast(                                    \
              int, __builtin_amdgcn_cvt_pkrtz(eB0, eB1));                      \
          const i32x2_t res = __builtin_amdgcn_permlane32_swap(A, B, false, false); \
          pw[t0] = res[0];                                                     \
          pw[t0 + 2] = res[1];                                                 \
        }                                                                      \
        pa[qs][ks] = __builtin_bit_cast(f16x8_t, pw);                          \
      }                                                                        \
      l_[qs] += xhalf_add(((rs0 + rs1) + (rs2 + rs3)));                        \
    }                                                                          \
    _Pragma("unroll") for (int ks = 0; ks < 4; ++ks) {                         \
      _Pragma("unroll") for (int ds = 0; ds < 2; ++ds) {                       \
        const f16x8_t vf = *reinterpret_cast<const f16x8_t*>(                  \
            Sall + 16384 + offj[ds * 4 + ks] + (BUFOFF));                      \
        o_[ds][0] = MFMA32(vf, pa[0][ks], o_[ds][0], 0, 0, 0);                 \
        o_[ds][1] = MFMA32(vf, pa[1][ks], o_[ds][1], 0, 0, 0);                 \
      }                                                                        \
    }                                                                          \
  } while (0)

__launch_bounds__(256, 2)
__global__ void attn(const f16* __restrict__ Qg, const f16* __restrict__ Kg,
                     const f16* __restrict__ Vt, float* __restrict__ out) {
  __shared__ __align__(16) char Sall[32768];
  const int tid = threadIdx.x;
  const int wid = tid >> 6, lane = tid & 63;
  const int r5 = lane & 31, hi = lane >> 5;

  const int bid = blockIdx.x;  // XCD grouping: head's 16 q-blocks on one XCD
  const int nh = (bid & 7) * 4 + ((bid >> 3) >> 4);
  const int qb = (bid >> 3) & 15;
  const int q0 = qb * 256 + wid * 64;

  const f16* Qb = Qg + (size_t)nh * SEQ * HDIM;
  const f16* Kb = Kg + (size_t)nh * SEQ * HDIM;
  const f16* Vb = Vt + (size_t)nh * HDIM * SEQ;

  // Precomputed swizzled LDS read offsets: C = j*32 + hi*16 (<256) per 256B row.
  const u32 x16 = (u32)(r5 & 15) << 4;
  u32 offj[8];
#pragma unroll
  for (int j = 0; j < 8; ++j)
    offj[j] = (u32)r5 * 256 + ((((u32)j) * 32 + (u32)hi * 16) ^ x16);

  // Staging source pointers (pre-swizzled, pointer-walked).
  const int c0 = wid * 2, c1 = c0 + 1;
  const char *kp0, *kp1, *vp0, *vp1;
  {
    const u32 lg0 = swz256((u32)c0 * 1024 + (u32)lane * 16);
    const u32 lg1 = swz256((u32)c1 * 1024 + (u32)lane * 16);
    const u32 row0 = (lg0 >> 8) + ((lg0 >> 7) & 1) * 32, cb0 = lg0 & 127;
    const u32 row1 = (lg1 >> 8) + ((lg1 >> 7) & 1) * 32, cb1 = lg1 & 127;
    kp0 = (const char*)Kb + (size_t)row0 * 128 + cb0;
    kp1 = (const char*)Kb + (size_t)row1 * 128 + cb1;
    vp0 = (const char*)Vb + (size_t)row0 * (SEQ * 2) + cb0;
    vp1 = (const char*)Vb + (size_t)row1 * (SEQ * 2) + cb1;
  }

  // Q fragments (pre-scaled by 0.125*log2e via Wq).
  f16x8_t qf[2][4];
#pragma unroll
  for (int qsub = 0; qsub < 2; ++qsub)
#pragma unroll
    for (int cs = 0; cs < 4; ++cs)
      qf[qsub][cs] = *reinterpret_cast<const f16x8_t*>(
          Qb + (size_t)(q0 + qsub * 32 + r5) * HDIM + cs * 16 + hi * 8);

  const f32x16_t fz = (f32x16_t)(0.f);
  f32x16_t o_[2][2];
#pragma unroll
  for (int a = 0; a < 2; ++a)
#pragma unroll
    for (int b = 0; b < 2; ++b) o_[a][b] = fz;
  float m_[2] = {-1e30f, -1e30f};
  float l_[2] = {0.f, 0.f};
  f16x8_t pa[2][4];

  // Prologue: stage tile 0 -> buf0.
  STAGE(0, 0);
  kp0 += 8192; kp1 += 8192;
  __syncthreads();

  for (int t2 = 0; t2 < 32; ++t2) {
    // half A: stage tile 2*t2+1 -> buf1, compute tile 2*t2 from buf0
    STAGE(8192, 128);
    kp0 += 8192; kp1 += 8192;
    COMPUTE(0);
    __syncthreads();
    // half B: stage tile 2*t2+2 -> buf0, compute tile 2*t2+1 from buf1
    if (t2 < 31) STAGE(0, 256);
    kp0 += 8192; kp1 += 8192;
    vp0 += 256; vp1 += 256;
    COMPUTE(8192);
    __syncthreads();
  }

  // Epilogue: O^T regs: col q lane-owned, row d = dsub*32 + 8j + 4hi + i.
  const int n = nh >> 4, h = nh & 15;
#pragma unroll
  for (int qsub = 0; qsub < 2; ++qsub) {
    const float invl = 1.0f / l_[qsub];
    const int q = q0 + qsub * 32 + r5;
    float* orow = out + ((size_t)(n * SEQ + q)) * DM + h * 64;
#pragma unroll
    for (int dsub = 0; dsub < 2; ++dsub)
#pragma unroll
      for (int j = 0; j < 4; ++j) {
        float4 v4;
        v4.x = o_[dsub][qsub][4 * j + 0] * invl;
        v4.y = o_[dsub][qsub][4 * j + 1] * invl;
        v4.z = o_[dsub][qsub][4 * j + 2] * invl;
        v4.w = o_[dsub][qsub][4 * j + 3] * invl;
        *reinterpret_cast<float4*>(orow + dsub * 32 + 8 * j + 4 * hi) = v4;
      }
  }
}

extern "C" void kernel_launch(void* const* d_in, const int* in_sizes, int n_in,
                              void* d_out, int out_size, void* d_ws, size_t ws_size,
                              hipStream_t stream) {
  const float* x  = (const float*)d_in[0];
  const float* Wq = (const float*)d_in[1];
  const float* Wk = (const float*)d_in[2];
  const float* Wv = (const float*)d_in[3];
  float* out = (float*)d_out;

  char* ws = (char*)d_ws;
  f16* xb = (f16*)(ws + 0);
  f16* wb = (f16*)(ws + 16777216);
  f16* Qg = (f16*)(ws + 23068672);
  f16* Kg = (f16*)(ws + 39845888);
  f16* Vt = (f16*)(ws + 56623104);

  cvt_f32_to_f16<<<2048, 256, 0, stream>>>(x, xb, NB * SEQ * DM / 4);
  cvt_w3<<<DM * DM / 4 / 256, 256, 0, stream>>>(Wq, Wk, Wv, wb);

  dim3 pgrid(NB * SEQ / PBM, (3 * DM) / PBN);  // 64 x 24
  qkv_proj<<<pgrid, 256, 0, stream>>>(xb, wb, Qg, Kg, Vt);

  attn<<<NB * NH * (SEQ / 256), 256, 0, stream>>>(Qg, Kg, Vt, out);
}